// Round 8
// baseline (2823.198 us; speedup 1.0000x reference)
//
#include <hip/hip_runtime.h>
#include <hip/hip_bf16.h>
#include <stdint.h>

// SAGE (GraphSAGE, LSTM aggregator). f32 I/O, bf16-granularity comparison ->
// bf16 MFMA internally. N=30000, DMAX=16, dims 128 -> 256 -> 64.
// R7 -> R8 (R7: 1644us; rec2 1192us at 2.44 TB/s service rate = L2-miss
// traffic bound: gather 0.96GB compulsory + Whh ~1.6GB L2 misses + spill):
//   M=128 nodes/WG, 1024 threads (16 waves = 4 row-groups x 4 col-waves):
//   - Whh request volume halves (same 512KB/WG-step over 2x nodes), and
//     WGs/XCD halve -> gather stream thrashes L2 half as hard -> Whh hits up.
//   - RT=2 per wave -> arch live ~85 < 128 VGPR cap -> ZERO spill
//     (kills R7's 234MB scratch WRITE + reloads).
//   - 16 waves/CU occupancy (was ~7) -> gather latency hiding.
// Verified layouts (learn_hip m89/m91): A[m=lane&15][k=q*8+j],
// D[row=q*4+r][col=lane&15]; W[4F,F] row-major == gemm-BT B-frag layout.

#define NN 30000
#define DMAXX 16

typedef __bf16 bf16_t;
typedef __bf16 bf16x8 __attribute__((ext_vector_type(8)));
typedef float f32x4 __attribute__((ext_vector_type(4)));
typedef unsigned short u16x4 __attribute__((ext_vector_type(4)));

// persistent scratch (fully rewritten every call; no cross-call state reuse)
__device__ __align__(16) bf16_t g_hbuf[(size_t)NN * 256];    // layer-1 output h1
__device__ __align__(16) bf16_t g_xg1[(size_t)NN * 512];     // feat@Wih1^T + biases
__device__ __align__(16) bf16_t g_xg2[(size_t)NN * 1024];    // h1@Wih2^T + biases
__device__ __align__(16) bf16_t g_wbuf[753664];              // bf16 weight copies

#define OFF_WIH1 0
#define OFF_WHH1 65536
#define OFF_WSELF1 131072
#define OFF_WNEIGH1 163840
#define OFF_WIH2 196608
#define OFF_WHH2 458752
#define OFF_WSELF2 720896
#define OFF_WNEIGH2 737280
#define W_TOTAL 753664

__global__ __launch_bounds__(256)
void cvt_weights(const float* __restrict__ s0, const float* __restrict__ s1,
                 const float* __restrict__ s2, const float* __restrict__ s3,
                 const float* __restrict__ s4, const float* __restrict__ s5,
                 const float* __restrict__ s6, const float* __restrict__ s7)
{
    int i = (blockIdx.x * 256 + threadIdx.x) * 4;
    if (i >= W_TOTAL) return;
    const float* src; int off;
    if      (i < OFF_WHH1)   { src = s0; off = OFF_WIH1; }
    else if (i < OFF_WSELF1) { src = s1; off = OFF_WHH1; }
    else if (i < OFF_WNEIGH1){ src = s2; off = OFF_WSELF1; }
    else if (i < OFF_WIH2)   { src = s3; off = OFF_WNEIGH1; }
    else if (i < OFF_WHH2)   { src = s4; off = OFF_WIH2; }
    else if (i < OFF_WSELF2) { src = s5; off = OFF_WHH2; }
    else if (i < OFF_WNEIGH2){ src = s6; off = OFF_WSELF2; }
    else                     { src = s7; off = OFF_WNEIGH2; }
    float4 v = *reinterpret_cast<const float4*>(src + (i - off));
    bf16_t o[4] __attribute__((aligned(8)));
    o[0] = (bf16_t)v.x; o[1] = (bf16_t)v.y; o[2] = (bf16_t)v.z; o[3] = (bf16_t)v.w;
    *reinterpret_cast<uint2*>(&g_wbuf[i]) = *reinterpret_cast<const uint2*>(o);
}

__device__ __forceinline__ float fsig(float x) { return 1.0f / (1.0f + __expf(-x)); }
__device__ __forceinline__ float ftanh(float x) { return 1.0f - 2.0f / (__expf(2.0f * x) + 1.0f); }
__device__ __forceinline__ float bf2f(unsigned short s) {
    union { unsigned u; float f; } v; v.u = ((unsigned)s) << 16; return v.f;
}

// stage an M-row x-tile (global, row-clamped) into LDS as bf16
template<int F, int M, int LDA, int NT, bool XF32>
__device__ __forceinline__ void stage_tile(bf16_t* dst, const void* src, int row0, int tid)
{
    constexpr int UN = F / 8;          // 16B(bf16) units per row
    for (int e = tid; e < M * UN; e += NT) {
        int m = e / UN, sub = e - m * UN;
        int row = row0 + m; if (row >= NN) row = NN - 1;
        if constexpr (XF32) {
            const float* p = (const float*)src + (size_t)row * F + sub * 8;
            float4 f0 = reinterpret_cast<const float4*>(p)[0];
            float4 f1 = reinterpret_cast<const float4*>(p)[1];
            bf16_t t[8] __attribute__((aligned(16)));
            t[0]=(bf16_t)f0.x; t[1]=(bf16_t)f0.y; t[2]=(bf16_t)f0.z; t[3]=(bf16_t)f0.w;
            t[4]=(bf16_t)f1.x; t[5]=(bf16_t)f1.y; t[6]=(bf16_t)f1.z; t[7]=(bf16_t)f1.w;
            *reinterpret_cast<uint4*>(&dst[m * LDA + sub * 8]) = *reinterpret_cast<const uint4*>(t);
        } else {
            const bf16_t* p = (const bf16_t*)src + (size_t)row * F + sub * 8;
            *reinterpret_cast<uint4*>(&dst[m * LDA + sub * 8]) = *reinterpret_cast<const uint4*>(p);
        }
    }
}

// xg[N, 4F] (gate-interleaved [c][g]) = x[N,F] @ W[4F,F]^T + b0 + b1
template<int F, int G, int NW, bool XF32>
__global__ __launch_bounds__(NW * 64, 2)
void xg_gemm(const void* __restrict__ xsrc_v, const bf16_t* __restrict__ W,
             const float* __restrict__ b0, const float* __restrict__ b1v,
             bf16_t* __restrict__ xg)
{
    constexpr int LDA = F + 8, KK = F / 32, NT = NW * 64;
    constexpr int CPW = G / NW;        // linear out-cols per wave
    constexpr int CT = CPW / 16;
    static_assert(CPW % 16 == 0 && F % 16 == 0, "");
    const int tid = threadIdx.x, wave = tid >> 6, lane = tid & 63;
    const int q = lane >> 4, m16 = lane & 15;
    const int row0 = blockIdx.x * 64;

    __shared__ __align__(16) bf16_t s_x[64 * LDA];
    stage_tile<F, 64, LDA, NT, XF32>(s_x, xsrc_v, row0, tid);
    __syncthreads();

    #pragma unroll
    for (int ct = 0; ct < CT; ++ct) {
        const int lc0 = wave * CPW + ct * 16;   // linear col block (within one gate)
        const int g = lc0 / F, c0 = lc0 - g * F;
        const float bias = b0[lc0 + m16] + b1v[lc0 + m16];
        f32x4 acc[4];
        #pragma unroll
        for (int rt = 0; rt < 4; ++rt)
            #pragma unroll
            for (int r = 0; r < 4; ++r) acc[rt][r] = bias;
        #pragma unroll
        for (int kk = 0; kk < KK; ++kk) {
            const int ko = kk * 32 + q * 8;
            bf16x8 b = *reinterpret_cast<const bf16x8*>(W + (size_t)(lc0 + m16) * F + ko);
            #pragma unroll
            for (int rt = 0; rt < 4; ++rt) {
                bf16x8 a = *reinterpret_cast<const bf16x8*>(&s_x[(rt * 16 + m16) * LDA + ko]);
                acc[rt] = __builtin_amdgcn_mfma_f32_16x16x32_bf16(a, b, acc[rt], 0, 0, 0);
            }
        }
        #pragma unroll
        for (int rt = 0; rt < 4; ++rt)
            #pragma unroll
            for (int r = 0; r < 4; ++r) {
                int row = row0 + rt * 16 + q * 4 + r;
                if (row < NN)
                    xg[(size_t)row * G + (size_t)(c0 + m16) * 4 + g] = (bf16_t)acc[rt][r];
            }
    }
}

// LSTM recurrence over gathered neighbors + fused fc epilogue.
// M=128 nodes/WG, 1024 threads = 16 waves: 4 row-groups (32 rows each,
// RT=2 16-row tiles) x 4 col-waves (CPW = F/4 cols each).
// gates = gather(xg) + h @ Whh^T ; out = x_self@Wself^T + h_fin@Wneigh^T + b
template<int F, int OUTF, bool RELU, bool XF32, typename OutT>
__global__ __launch_bounds__(1024, 4)
void sage_rec(const void* __restrict__ xself_v,
              const bf16_t* __restrict__ xg,
              const int* __restrict__ nbr_idx, const int* __restrict__ deg,
              const bf16_t* __restrict__ Whh,
              const bf16_t* __restrict__ Wself, const bf16_t* __restrict__ Wneigh,
              const float* __restrict__ bout, OutT* __restrict__ outp)
{
    constexpr int M = 128, NT = 1024, NW = 16, RT = 2;
    constexpr int LDA = F + 8, KK = F / 32;
    constexpr int CPW = F / 4, CT = CPW / 16, G4 = 4 * F;
    static_assert(CPW % 16 == 0, "");
    static_assert((DMAXX & 1) == 0, "final h must land in buf[0]");
    const int tid = threadIdx.x, wave = tid >> 6, lane = tid & 63;
    const int q = lane >> 4, m16 = lane & 15;
    const int rg = wave >> 2;          // row-group: rows rg*32 .. rg*32+31
    const int cw = wave & 3;           // col-wave:  cols cw*CPW ..
    const int node0 = blockIdx.x * M;

    __shared__ __align__(16) bf16_t s_h[2][M * LDA];   // double-buffered h
    __shared__ int s_idx[M * DMAXX];
    __shared__ int s_deg[M];

    for (int i = tid; i < M * DMAXX; i += NT) {
        int m = i >> 4;
        int node = node0 + m; if (node >= NN) node = NN - 1;
        int v = nbr_idx[node * DMAXX + (i & 15)];
        if (v < 0) v = 0; if (v >= NN) v = NN - 1;
        s_idx[i] = v;
    }
    for (int i = tid; i < M; i += NT) {
        int node = node0 + i; if (node >= NN) node = NN - 1;
        s_deg[i] = deg[node];
    }
    for (int i = tid; i < M * LDA; i += NT) s_h[0][i] = (bf16_t)0.0f;
    __syncthreads();

    int dg[RT][4];
    #pragma unroll
    for (int rt = 0; rt < RT; ++rt)
        #pragma unroll
        for (int r = 0; r < 4; ++r)
            dg[rt][r] = s_deg[rg * 32 + rt * 16 + q * 4 + r];

    f32x4 c_[RT][CT];
    #pragma unroll
    for (int rt = 0; rt < RT; ++rt)
        #pragma unroll
        for (int ct = 0; ct < CT; ++ct)
            #pragma unroll
            for (int r = 0; r < 4; ++r) c_[rt][ct][r] = 0.0f;

    #pragma unroll 1
    for (int t = 0; t < DMAXX; ++t) {
        const bf16_t* cur = s_h[t & 1];
        bf16_t* nxt = s_h[(t + 1) & 1];
        #pragma unroll
        for (int ct = 0; ct < CT; ++ct) {
            // gather gate-init (xg = x@Wih^T + biases), 8B/elem
            u16x4 u[RT][4];
            #pragma unroll
            for (int rt = 0; rt < RT; ++rt)
                #pragma unroll
                for (int r = 0; r < 4; ++r) {
                    int row = s_idx[(rg * 32 + rt * 16 + q * 4 + r) * DMAXX + t];
                    u[rt][r] = *reinterpret_cast<const u16x4*>(
                        xg + (size_t)row * G4 + (size_t)(cw * CPW + ct * 16 + m16) * 4);
                }
            f32x4 acc[RT][4];
            #pragma unroll
            for (int rt = 0; rt < RT; ++rt)
                #pragma unroll
                for (int g = 0; g < 4; ++g)
                    #pragma unroll
                    for (int r = 0; r < 4; ++r) acc[rt][g][r] = 0.0f;
            #pragma unroll
            for (int kk = 0; kk < KK; ++kk) {
                const int ko = kk * 32 + q * 8;
                bf16x8 ah[RT];
                #pragma unroll
                for (int rt = 0; rt < RT; ++rt)
                    ah[rt] = *reinterpret_cast<const bf16x8*>(
                        &cur[(rg * 32 + rt * 16 + m16) * LDA + ko]);
                #pragma unroll
                for (int g = 0; g < 4; ++g) {
                    bf16x8 bh = *reinterpret_cast<const bf16x8*>(
                        Whh + (size_t)(g * F + cw * CPW + ct * 16 + m16) * F + ko);
                    #pragma unroll
                    for (int rt = 0; rt < RT; ++rt)
                        acc[rt][g] = __builtin_amdgcn_mfma_f32_16x16x32_bf16(ah[rt], bh, acc[rt][g], 0, 0, 0);
                }
            }
            // pointwise LSTM update + masked store:
            //   t <  deg : write h_new (and update c)
            //   t == deg : copy frozen h from cur
            //   t >  deg : skip -- nxt already holds the frozen value
            #pragma unroll
            for (int rt = 0; rt < RT; ++rt)
                #pragma unroll
                for (int r = 0; r < 4; ++r) {
                    float iv = fsig (acc[rt][0][r] + bf2f(u[rt][r].x));
                    float fv = fsig (acc[rt][1][r] + bf2f(u[rt][r].y));
                    float gv = ftanh(acc[rt][2][r] + bf2f(u[rt][r].z));
                    float ov = fsig (acc[rt][3][r] + bf2f(u[rt][r].w));
                    float cn = fv * c_[rt][ct][r] + iv * gv;
                    float hv = ov * ftanh(cn);
                    const int pos = (rg * 32 + rt * 16 + q * 4 + r) * LDA
                                  + cw * CPW + ct * 16 + m16;
                    int d = dg[rt][r];
                    if (t < d) {
                        c_[rt][ct][r] = cn;
                        nxt[pos] = (bf16_t)hv;
                    } else if (t == d) {
                        reinterpret_cast<unsigned short*>(nxt)[pos] =
                            reinterpret_cast<const unsigned short*>(cur)[pos];
                    }
                }
        }
        __syncthreads();   // nxt fully written; cur fully consumed
    }

    // final h is in s_h[0]; stage self-rows into retired s_h[1] for epilogue
    stage_tile<F, M, LDA, NT, XF32>(s_h[1], xself_v, node0, tid);
    __syncthreads();

    // epilogue: out = x_self @ Wself^T + h_fin @ Wneigh^T + bout (+relu)
    constexpr int NCT = OUTF / 16;
    constexpr int TILES = NCT * (M / 16);
    constexpr int TPW = TILES / NW;
    static_assert(TILES % NW == 0, "");
    #pragma unroll
    for (int tt = 0; tt < TPW; ++tt) {
        int tile = wave * TPW + tt;
        int ot = tile % NCT, rtile = tile / NCT;
        f32x4 o;
        o[0] = 0.f; o[1] = 0.f; o[2] = 0.f; o[3] = 0.f;
        #pragma unroll
        for (int kk = 0; kk < KK; ++kk) {
            const int ko = kk * 32 + q * 8;
            bf16x8 axs = *reinterpret_cast<const bf16x8*>(&s_h[1][(rtile * 16 + m16) * LDA + ko]);
            bf16x8 am  = *reinterpret_cast<const bf16x8*>(&s_h[0][(rtile * 16 + m16) * LDA + ko]);
            bf16x8 bs = *reinterpret_cast<const bf16x8*>(Wself  + (size_t)(ot * 16 + m16) * F + ko);
            bf16x8 bn = *reinterpret_cast<const bf16x8*>(Wneigh + (size_t)(ot * 16 + m16) * F + ko);
            o = __builtin_amdgcn_mfma_f32_16x16x32_bf16(axs, bs, o, 0, 0, 0);
            o = __builtin_amdgcn_mfma_f32_16x16x32_bf16(am,  bn, o, 0, 0, 0);
        }
        int ocol = ot * 16 + m16;
        float bias = bout[ocol];
        #pragma unroll
        for (int r = 0; r < 4; ++r) {
            int node = node0 + rtile * 16 + q * 4 + r;
            if (node < NN) {
                float v = o[r] + bias;
                if (RELU) v = fmaxf(v, 0.0f);
                outp[(size_t)node * OUTF + ocol] = (OutT)v;
            }
        }
    }
}

extern "C" void kernel_launch(void* const* d_in, const int* in_sizes, int n_in,
                              void* d_out, int out_size, void* d_ws, size_t ws_size,
                              hipStream_t stream)
{
    const float* feat    = (const float*)d_in[0];
    const int*   nbr     = (const int*)d_in[1];
    const int*   degp    = (const int*)d_in[2];
    const float* Wih1    = (const float*)d_in[3];
    const float* Whh1    = (const float*)d_in[4];
    const float* bih1    = (const float*)d_in[5];
    const float* bhh1    = (const float*)d_in[6];
    const float* Wself1  = (const float*)d_in[7];
    const float* Wneigh1 = (const float*)d_in[8];
    const float* b1      = (const float*)d_in[9];
    const float* Wih2    = (const float*)d_in[10];
    const float* Whh2    = (const float*)d_in[11];
    const float* bih2    = (const float*)d_in[12];
    const float* bhh2    = (const float*)d_in[13];
    const float* Wself2  = (const float*)d_in[14];
    const float* Wneigh2 = (const float*)d_in[15];
    const float* b2      = (const float*)d_in[16];

    bf16_t *hglob, *wglob, *xg1, *xg2;
    hipGetSymbolAddress((void**)&hglob, HIP_SYMBOL(g_hbuf));
    hipGetSymbolAddress((void**)&wglob, HIP_SYMBOL(g_wbuf));
    hipGetSymbolAddress((void**)&xg1,   HIP_SYMBOL(g_xg1));
    hipGetSymbolAddress((void**)&xg2,   HIP_SYMBOL(g_xg2));

    cvt_weights<<<W_TOTAL / 4 / 256, 256, 0, stream>>>(
        Wih1, Whh1, Wself1, Wneigh1, Wih2, Whh2, Wself2, Wneigh2);

    const int grid64  = (NN + 63) / 64;    // 469 WGs (xg gemms)
    const int grid128 = (NN + 127) / 128;  // 235 WGs (recurrences)

    xg_gemm<128, 512, 8, true><<<grid64, 512, 0, stream>>>(
        feat, wglob + OFF_WIH1, bih1, bhh1, xg1);

    sage_rec<128, 256, true, true, bf16_t><<<grid128, 1024, 0, stream>>>(
        feat, xg1, nbr, degp, wglob + OFF_WHH1,
        wglob + OFF_WSELF1, wglob + OFF_WNEIGH1, b1, hglob);

    xg_gemm<256, 1024, 8, false><<<grid64, 512, 0, stream>>>(
        hglob, wglob + OFF_WIH2, bih2, bhh2, xg2);

    sage_rec<256, 64, false, false, float><<<grid128, 1024, 0, stream>>>(
        hglob, xg2, nbr, degp, wglob + OFF_WHH2,
        wglob + OFF_WSELF2, wglob + OFF_WNEIGH2, b2, (float*)d_out);
}

// Round 9
// 2333.270 us; speedup vs baseline: 1.2100x; 1.2100x over previous
//
#include <hip/hip_runtime.h>
#include <hip/hip_bf16.h>
#include <stdint.h>

// SAGE (GraphSAGE, LSTM aggregator). f32 I/O, bf16-granularity comparison ->
// bf16 MFMA internally. N=30000, DMAX=16, dims 128 -> 256 -> 64.
// R8 -> R9: R8 (M=128/1024thr) regressed: 16-wave WG forces 4 waves/EU ->
// 128-reg unified budget -> 64 arch VGPRs -> heavy spill (629MB WRITE).
// Revert to R7 structure (M=64, 512thr, (512,2)) and kill its residual
// 234MB spill by shrinking the live set:
//   1. 2 row-groups x 4 col-waves: RT=2 -> acc AGPRs 64->32, u regs 32->16.
//   2. s_idx holds PRE-SCALED 32-bit byte offsets (row*4F*2) -> gathers are
//      SGPR-base + u32 voffset (halves address regs).
//   3. deg packed 4-per-int (16 -> 2 VGPRs).
// Arch live ~85 < 128 -> zero spill at the same occupancy.
// Verified layouts (learn_hip m89/m91): A[m=lane&15][k=q*8+j],
// D[row=q*4+r][col=lane&15]; W[4F,F] row-major == gemm-BT B-frag layout.

#define NN 30000
#define DMAXX 16

typedef __bf16 bf16_t;
typedef __bf16 bf16x8 __attribute__((ext_vector_type(8)));
typedef float f32x4 __attribute__((ext_vector_type(4)));
typedef unsigned short u16x4 __attribute__((ext_vector_type(4)));

// persistent scratch (fully rewritten every call; no cross-call state reuse)
__device__ __align__(16) bf16_t g_hbuf[(size_t)NN * 256];    // layer-1 output h1
__device__ __align__(16) bf16_t g_xg1[(size_t)NN * 512];     // feat@Wih1^T + biases
__device__ __align__(16) bf16_t g_xg2[(size_t)NN * 1024];    // h1@Wih2^T + biases
__device__ __align__(16) bf16_t g_wbuf[753664];              // bf16 weight copies

#define OFF_WIH1 0
#define OFF_WHH1 65536
#define OFF_WSELF1 131072
#define OFF_WNEIGH1 163840
#define OFF_WIH2 196608
#define OFF_WHH2 458752
#define OFF_WSELF2 720896
#define OFF_WNEIGH2 737280
#define W_TOTAL 753664

__global__ __launch_bounds__(256)
void cvt_weights(const float* __restrict__ s0, const float* __restrict__ s1,
                 const float* __restrict__ s2, const float* __restrict__ s3,
                 const float* __restrict__ s4, const float* __restrict__ s5,
                 const float* __restrict__ s6, const float* __restrict__ s7)
{
    int i = (blockIdx.x * 256 + threadIdx.x) * 4;
    if (i >= W_TOTAL) return;
    const float* src; int off;
    if      (i < OFF_WHH1)   { src = s0; off = OFF_WIH1; }
    else if (i < OFF_WSELF1) { src = s1; off = OFF_WHH1; }
    else if (i < OFF_WNEIGH1){ src = s2; off = OFF_WSELF1; }
    else if (i < OFF_WIH2)   { src = s3; off = OFF_WNEIGH1; }
    else if (i < OFF_WHH2)   { src = s4; off = OFF_WIH2; }
    else if (i < OFF_WSELF2) { src = s5; off = OFF_WHH2; }
    else if (i < OFF_WNEIGH2){ src = s6; off = OFF_WSELF2; }
    else                     { src = s7; off = OFF_WNEIGH2; }
    float4 v = *reinterpret_cast<const float4*>(src + (i - off));
    bf16_t o[4] __attribute__((aligned(8)));
    o[0] = (bf16_t)v.x; o[1] = (bf16_t)v.y; o[2] = (bf16_t)v.z; o[3] = (bf16_t)v.w;
    *reinterpret_cast<uint2*>(&g_wbuf[i]) = *reinterpret_cast<const uint2*>(o);
}

__device__ __forceinline__ float fsig(float x) { return 1.0f / (1.0f + __expf(-x)); }
__device__ __forceinline__ float ftanh(float x) { return 1.0f - 2.0f / (__expf(2.0f * x) + 1.0f); }
__device__ __forceinline__ float bf2f(unsigned short s) {
    union { unsigned u; float f; } v; v.u = ((unsigned)s) << 16; return v.f;
}

// stage an M-row x-tile (global, row-clamped) into LDS as bf16
template<int F, int M, int LDA, int NT, bool XF32>
__device__ __forceinline__ void stage_tile(bf16_t* dst, const void* src, int row0, int tid)
{
    constexpr int UN = F / 8;          // 16B(bf16) units per row
    for (int e = tid; e < M * UN; e += NT) {
        int m = e / UN, sub = e - m * UN;
        int row = row0 + m; if (row >= NN) row = NN - 1;
        if constexpr (XF32) {
            const float* p = (const float*)src + (size_t)row * F + sub * 8;
            float4 f0 = reinterpret_cast<const float4*>(p)[0];
            float4 f1 = reinterpret_cast<const float4*>(p)[1];
            bf16_t t[8] __attribute__((aligned(16)));
            t[0]=(bf16_t)f0.x; t[1]=(bf16_t)f0.y; t[2]=(bf16_t)f0.z; t[3]=(bf16_t)f0.w;
            t[4]=(bf16_t)f1.x; t[5]=(bf16_t)f1.y; t[6]=(bf16_t)f1.z; t[7]=(bf16_t)f1.w;
            *reinterpret_cast<uint4*>(&dst[m * LDA + sub * 8]) = *reinterpret_cast<const uint4*>(t);
        } else {
            const bf16_t* p = (const bf16_t*)src + (size_t)row * F + sub * 8;
            *reinterpret_cast<uint4*>(&dst[m * LDA + sub * 8]) = *reinterpret_cast<const uint4*>(p);
        }
    }
}

// xg[N, 4F] (gate-interleaved [c][g]) = x[N,F] @ W[4F,F]^T + b0 + b1
template<int F, int G, int NW, bool XF32>
__global__ __launch_bounds__(NW * 64, 2)
void xg_gemm(const void* __restrict__ xsrc_v, const bf16_t* __restrict__ W,
             const float* __restrict__ b0, const float* __restrict__ b1v,
             bf16_t* __restrict__ xg)
{
    constexpr int LDA = F + 8, KK = F / 32, NT = NW * 64;
    constexpr int CPW = G / NW;        // linear out-cols per wave
    constexpr int CT = CPW / 16;
    static_assert(CPW % 16 == 0 && F % 16 == 0, "");
    const int tid = threadIdx.x, wave = tid >> 6, lane = tid & 63;
    const int q = lane >> 4, m16 = lane & 15;
    const int row0 = blockIdx.x * 64;

    __shared__ __align__(16) bf16_t s_x[64 * LDA];
    stage_tile<F, 64, LDA, NT, XF32>(s_x, xsrc_v, row0, tid);
    __syncthreads();

    #pragma unroll
    for (int ct = 0; ct < CT; ++ct) {
        const int lc0 = wave * CPW + ct * 16;   // linear col block (within one gate)
        const int g = lc0 / F, c0 = lc0 - g * F;
        const float bias = b0[lc0 + m16] + b1v[lc0 + m16];
        f32x4 acc[4];
        #pragma unroll
        for (int rt = 0; rt < 4; ++rt)
            #pragma unroll
            for (int r = 0; r < 4; ++r) acc[rt][r] = bias;
        #pragma unroll
        for (int kk = 0; kk < KK; ++kk) {
            const int ko = kk * 32 + q * 8;
            bf16x8 b = *reinterpret_cast<const bf16x8*>(W + (size_t)(lc0 + m16) * F + ko);
            #pragma unroll
            for (int rt = 0; rt < 4; ++rt) {
                bf16x8 a = *reinterpret_cast<const bf16x8*>(&s_x[(rt * 16 + m16) * LDA + ko]);
                acc[rt] = __builtin_amdgcn_mfma_f32_16x16x32_bf16(a, b, acc[rt], 0, 0, 0);
            }
        }
        #pragma unroll
        for (int rt = 0; rt < 4; ++rt)
            #pragma unroll
            for (int r = 0; r < 4; ++r) {
                int row = row0 + rt * 16 + q * 4 + r;
                if (row < NN)
                    xg[(size_t)row * G + (size_t)(c0 + m16) * 4 + g] = (bf16_t)acc[rt][r];
            }
    }
}

// LSTM recurrence over gathered neighbors + fused fc epilogue.
// M=64 nodes/WG, 512 threads = 8 waves: 2 row-groups (32 rows) x 4 col-waves
// (CPW = F/4 cols). RT=2 -> acc = 32 AGPRs, arch live ~85 -> no spill.
// gates = gather(xg) + h @ Whh^T ; out = x_self@Wself^T + h_fin@Wneigh^T + b
template<int F, int OUTF, bool RELU, bool XF32, typename OutT>
__global__ __launch_bounds__(512, 2)
void sage_rec(const void* __restrict__ xself_v,
              const bf16_t* __restrict__ xg,
              const int* __restrict__ nbr_idx, const int* __restrict__ deg,
              const bf16_t* __restrict__ Whh,
              const bf16_t* __restrict__ Wself, const bf16_t* __restrict__ Wneigh,
              const float* __restrict__ bout, OutT* __restrict__ outp)
{
    constexpr int M = 64, NT = 512, NW = 8, RT = 2;
    constexpr int LDA = F + 8, KK = F / 32;
    constexpr int CPW = F / 4, CT = CPW / 16, G4 = 4 * F;
    static_assert(CPW % 16 == 0, "");
    static_assert((DMAXX & 1) == 0, "final h must land in buf[0]");
    const int tid = threadIdx.x, wave = tid >> 6, lane = tid & 63;
    const int q = lane >> 4, m16 = lane & 15;
    const int rg = wave >> 2;          // row-group: rows rg*32 .. rg*32+31
    const int cw = wave & 3;           // col-wave:  cols cw*CPW ..
    const int node0 = blockIdx.x * M;

    __shared__ __align__(16) bf16_t s_h[2][M * LDA];   // double-buffered h
    __shared__ int s_idx[M * DMAXX];                   // PRE-SCALED byte offsets
    __shared__ int s_deg[M];

    for (int i = tid; i < M * DMAXX; i += NT) {
        int m = i >> 4;
        int node = node0 + m; if (node >= NN) node = NN - 1;
        int v = nbr_idx[node * DMAXX + (i & 15)];
        if (v < 0) v = 0; if (v >= NN) v = NN - 1;
        s_idx[i] = v * (G4 * 2);       // byte offset of row v in xg
    }
    for (int i = tid; i < M; i += NT) {
        int node = node0 + i; if (node >= NN) node = NN - 1;
        s_deg[i] = deg[node];
    }
    for (int i = tid; i < M * LDA; i += NT) s_h[0][i] = (bf16_t)0.0f;
    __syncthreads();

    // packed degrees: 4x 8-bit per int, one int per row-tile
    int dgp[RT];
    #pragma unroll
    for (int rt = 0; rt < RT; ++rt) {
        int p = 0;
        #pragma unroll
        for (int r = 0; r < 4; ++r)
            p |= (s_deg[rg * 32 + rt * 16 + q * 4 + r] & 255) << (8 * r);
        dgp[rt] = p;
    }

    f32x4 c_[RT][CT];
    #pragma unroll
    for (int rt = 0; rt < RT; ++rt)
        #pragma unroll
        for (int ct = 0; ct < CT; ++ct)
            #pragma unroll
            for (int r = 0; r < 4; ++r) c_[rt][ct][r] = 0.0f;

    const char* xgb = (const char*)xg;

    #pragma unroll 1
    for (int t = 0; t < DMAXX; ++t) {
        const bf16_t* cur = s_h[t & 1];
        bf16_t* nxt = s_h[(t + 1) & 1];
        #pragma unroll
        for (int ct = 0; ct < CT; ++ct) {
            const int colb = (cw * CPW + ct * 16 + m16) * 8;   // col byte offset
            // gather gate-init (xg = x@Wih^T + biases), 8B/elem
            u16x4 u[RT][4];
            #pragma unroll
            for (int rt = 0; rt < RT; ++rt)
                #pragma unroll
                for (int r = 0; r < 4; ++r) {
                    int off = s_idx[(rg * 32 + rt * 16 + q * 4 + r) * DMAXX + t];
                    u[rt][r] = *reinterpret_cast<const u16x4*>(xgb + (unsigned)(off + colb));
                }
            f32x4 acc[RT][4];
            #pragma unroll
            for (int rt = 0; rt < RT; ++rt)
                #pragma unroll
                for (int g = 0; g < 4; ++g)
                    #pragma unroll
                    for (int r = 0; r < 4; ++r) acc[rt][g][r] = 0.0f;
            #pragma unroll
            for (int kk = 0; kk < KK; ++kk) {
                const int ko = kk * 32 + q * 8;
                bf16x8 ah[RT];
                #pragma unroll
                for (int rt = 0; rt < RT; ++rt)
                    ah[rt] = *reinterpret_cast<const bf16x8*>(
                        &cur[(rg * 32 + rt * 16 + m16) * LDA + ko]);
                #pragma unroll
                for (int g = 0; g < 4; ++g) {
                    bf16x8 bh = *reinterpret_cast<const bf16x8*>(
                        Whh + (size_t)(g * F + cw * CPW + ct * 16 + m16) * F + ko);
                    #pragma unroll
                    for (int rt = 0; rt < RT; ++rt)
                        acc[rt][g] = __builtin_amdgcn_mfma_f32_16x16x32_bf16(ah[rt], bh, acc[rt][g], 0, 0, 0);
                }
            }
            // pointwise LSTM update + masked store:
            //   t <  deg : write h_new (and update c)
            //   t == deg : copy frozen h from cur
            //   t >  deg : skip -- nxt already holds the frozen value
            #pragma unroll
            for (int rt = 0; rt < RT; ++rt)
                #pragma unroll
                for (int r = 0; r < 4; ++r) {
                    float iv = fsig (acc[rt][0][r] + bf2f(u[rt][r].x));
                    float fv = fsig (acc[rt][1][r] + bf2f(u[rt][r].y));
                    float gv = ftanh(acc[rt][2][r] + bf2f(u[rt][r].z));
                    float ov = fsig (acc[rt][3][r] + bf2f(u[rt][r].w));
                    float cn = fv * c_[rt][ct][r] + iv * gv;
                    float hv = ov * ftanh(cn);
                    const int pos = (rg * 32 + rt * 16 + q * 4 + r) * LDA
                                  + cw * CPW + ct * 16 + m16;
                    const int d = (dgp[rt] >> (8 * r)) & 255;
                    if (t < d) {
                        c_[rt][ct][r] = cn;
                        nxt[pos] = (bf16_t)hv;
                    } else if (t == d) {
                        reinterpret_cast<unsigned short*>(nxt)[pos] =
                            reinterpret_cast<const unsigned short*>(cur)[pos];
                    }
                }
        }
        __syncthreads();   // nxt fully written; cur fully consumed
    }

    // final h is in s_h[0]; stage self-rows into retired s_h[1] for epilogue
    stage_tile<F, M, LDA, NT, XF32>(s_h[1], xself_v, node0, tid);
    __syncthreads();

    // epilogue: out = x_self @ Wself^T + h_fin @ Wneigh^T + bout (+relu)
    constexpr int NCT = OUTF / 16;
    constexpr int TILES = NCT * (M / 16);
    constexpr int TPW = TILES / NW;
    static_assert(TILES % NW == 0, "");
    #pragma unroll
    for (int tt = 0; tt < TPW; ++tt) {
        int tile = wave * TPW + tt;
        int ot = tile % NCT, rtile = tile / NCT;
        f32x4 o;
        o[0] = 0.f; o[1] = 0.f; o[2] = 0.f; o[3] = 0.f;
        #pragma unroll
        for (int kk = 0; kk < KK; ++kk) {
            const int ko = kk * 32 + q * 8;
            bf16x8 axs = *reinterpret_cast<const bf16x8*>(&s_h[1][(rtile * 16 + m16) * LDA + ko]);
            bf16x8 am  = *reinterpret_cast<const bf16x8*>(&s_h[0][(rtile * 16 + m16) * LDA + ko]);
            bf16x8 bs = *reinterpret_cast<const bf16x8*>(Wself  + (size_t)(ot * 16 + m16) * F + ko);
            bf16x8 bn = *reinterpret_cast<const bf16x8*>(Wneigh + (size_t)(ot * 16 + m16) * F + ko);
            o = __builtin_amdgcn_mfma_f32_16x16x32_bf16(axs, bs, o, 0, 0, 0);
            o = __builtin_amdgcn_mfma_f32_16x16x32_bf16(am,  bn, o, 0, 0, 0);
        }
        int ocol = ot * 16 + m16;
        float bias = bout[ocol];
        #pragma unroll
        for (int r = 0; r < 4; ++r) {
            int node = node0 + rtile * 16 + q * 4 + r;
            if (node < NN) {
                float v = o[r] + bias;
                if (RELU) v = fmaxf(v, 0.0f);
                outp[(size_t)node * OUTF + ocol] = (OutT)v;
            }
        }
    }
}

extern "C" void kernel_launch(void* const* d_in, const int* in_sizes, int n_in,
                              void* d_out, int out_size, void* d_ws, size_t ws_size,
                              hipStream_t stream)
{
    const float* feat    = (const float*)d_in[0];
    const int*   nbr     = (const int*)d_in[1];
    const int*   degp    = (const int*)d_in[2];
    const float* Wih1    = (const float*)d_in[3];
    const float* Whh1    = (const float*)d_in[4];
    const float* bih1    = (const float*)d_in[5];
    const float* bhh1    = (const float*)d_in[6];
    const float* Wself1  = (const float*)d_in[7];
    const float* Wneigh1 = (const float*)d_in[8];
    const float* b1      = (const float*)d_in[9];
    const float* Wih2    = (const float*)d_in[10];
    const float* Whh2    = (const float*)d_in[11];
    const float* bih2    = (const float*)d_in[12];
    const float* bhh2    = (const float*)d_in[13];
    const float* Wself2  = (const float*)d_in[14];
    const float* Wneigh2 = (const float*)d_in[15];
    const float* b2      = (const float*)d_in[16];

    bf16_t *hglob, *wglob, *xg1, *xg2;
    hipGetSymbolAddress((void**)&hglob, HIP_SYMBOL(g_hbuf));
    hipGetSymbolAddress((void**)&wglob, HIP_SYMBOL(g_wbuf));
    hipGetSymbolAddress((void**)&xg1,   HIP_SYMBOL(g_xg1));
    hipGetSymbolAddress((void**)&xg2,   HIP_SYMBOL(g_xg2));

    cvt_weights<<<W_TOTAL / 4 / 256, 256, 0, stream>>>(
        Wih1, Whh1, Wself1, Wneigh1, Wih2, Whh2, Wself2, Wneigh2);

    const int grid = (NN + 63) / 64;   // 469 WGs

    xg_gemm<128, 512, 8, true><<<grid, 512, 0, stream>>>(
        feat, wglob + OFF_WIH1, bih1, bhh1, xg1);

    sage_rec<128, 256, true, true, bf16_t><<<grid, 512, 0, stream>>>(
        feat, xg1, nbr, degp, wglob + OFF_WHH1,
        wglob + OFF_WSELF1, wglob + OFF_WNEIGH1, b1, hglob);

    xg_gemm<256, 1024, 8, false><<<grid, 512, 0, stream>>>(
        hglob, wglob + OFF_WIH2, bih2, bhh2, xg2);

    sage_rec<256, 64, false, false, float><<<grid, 512, 0, stream>>>(
        hglob, xg2, nbr, degp, wglob + OFF_WHH2,
        wglob + OFF_WSELF2, wglob + OFF_WNEIGH2, b2, (float*)d_out);
}

// Round 10
// 2102.848 us; speedup vs baseline: 1.3426x; 1.1096x over previous
//
#include <hip/hip_runtime.h>
#include <hip/hip_bf16.h>
#include <stdint.h>

// SAGE (GraphSAGE, LSTM aggregator). f32 I/O, bf16-granularity comparison ->
// bf16 MFMA internally. N=30000, DMAX=16, dims 128 -> 256 -> 64.
// R9 -> R10 (R9: regressed, FETCH 3.87GB ~= Whh missing L2 every request +
// spill reloads; unrolled ct-loop let LLVM hoist all gathers -> spill anyway):
//   1. #pragma unroll 1 on the ct-loop: no cross-ct gather hoisting.
//   2. Gathers folded straight into acc init (gates are linear in xg):
//      u dies at iteration top instead of living across 64 MFMAs.
//      Per-iter live ~55 arch + 32 AGPR -> genuinely spill-free.
//   3. Regs<=128 + LDS 72KB<=80KB -> 2 WGs/CU co-resident (16 waves/CU).
// Verified layouts (learn_hip m89/m91): A[m=lane&15][k=q*8+j],
// D[row=q*4+r][col=lane&15]; W[4F,F] row-major == gemm-BT B-frag layout.

#define NN 30000
#define DMAXX 16

typedef __bf16 bf16_t;
typedef __bf16 bf16x8 __attribute__((ext_vector_type(8)));
typedef float f32x4 __attribute__((ext_vector_type(4)));
typedef unsigned short u16x4 __attribute__((ext_vector_type(4)));

// persistent scratch (fully rewritten every call; no cross-call state reuse)
__device__ __align__(16) bf16_t g_hbuf[(size_t)NN * 256];    // layer-1 output h1
__device__ __align__(16) bf16_t g_xg1[(size_t)NN * 512];     // feat@Wih1^T + biases
__device__ __align__(16) bf16_t g_xg2[(size_t)NN * 1024];    // h1@Wih2^T + biases
__device__ __align__(16) bf16_t g_wbuf[753664];              // bf16 weight copies

#define OFF_WIH1 0
#define OFF_WHH1 65536
#define OFF_WSELF1 131072
#define OFF_WNEIGH1 163840
#define OFF_WIH2 196608
#define OFF_WHH2 458752
#define OFF_WSELF2 720896
#define OFF_WNEIGH2 737280
#define W_TOTAL 753664

__global__ __launch_bounds__(256)
void cvt_weights(const float* __restrict__ s0, const float* __restrict__ s1,
                 const float* __restrict__ s2, const float* __restrict__ s3,
                 const float* __restrict__ s4, const float* __restrict__ s5,
                 const float* __restrict__ s6, const float* __restrict__ s7)
{
    int i = (blockIdx.x * 256 + threadIdx.x) * 4;
    if (i >= W_TOTAL) return;
    const float* src; int off;
    if      (i < OFF_WHH1)   { src = s0; off = OFF_WIH1; }
    else if (i < OFF_WSELF1) { src = s1; off = OFF_WHH1; }
    else if (i < OFF_WNEIGH1){ src = s2; off = OFF_WSELF1; }
    else if (i < OFF_WIH2)   { src = s3; off = OFF_WNEIGH1; }
    else if (i < OFF_WHH2)   { src = s4; off = OFF_WIH2; }
    else if (i < OFF_WSELF2) { src = s5; off = OFF_WHH2; }
    else if (i < OFF_WNEIGH2){ src = s6; off = OFF_WSELF2; }
    else                     { src = s7; off = OFF_WNEIGH2; }
    float4 v = *reinterpret_cast<const float4*>(src + (i - off));
    bf16_t o[4] __attribute__((aligned(8)));
    o[0] = (bf16_t)v.x; o[1] = (bf16_t)v.y; o[2] = (bf16_t)v.z; o[3] = (bf16_t)v.w;
    *reinterpret_cast<uint2*>(&g_wbuf[i]) = *reinterpret_cast<const uint2*>(o);
}

__device__ __forceinline__ float fsig(float x) { return 1.0f / (1.0f + __expf(-x)); }
__device__ __forceinline__ float ftanh(float x) { return 1.0f - 2.0f / (__expf(2.0f * x) + 1.0f); }
__device__ __forceinline__ float bf2f(unsigned short s) {
    union { unsigned u; float f; } v; v.u = ((unsigned)s) << 16; return v.f;
}

// stage an M-row x-tile (global, row-clamped) into LDS as bf16
template<int F, int M, int LDA, int NT, bool XF32>
__device__ __forceinline__ void stage_tile(bf16_t* dst, const void* src, int row0, int tid)
{
    constexpr int UN = F / 8;          // 16B(bf16) units per row
    for (int e = tid; e < M * UN; e += NT) {
        int m = e / UN, sub = e - m * UN;
        int row = row0 + m; if (row >= NN) row = NN - 1;
        if constexpr (XF32) {
            const float* p = (const float*)src + (size_t)row * F + sub * 8;
            float4 f0 = reinterpret_cast<const float4*>(p)[0];
            float4 f1 = reinterpret_cast<const float4*>(p)[1];
            bf16_t t[8] __attribute__((aligned(16)));
            t[0]=(bf16_t)f0.x; t[1]=(bf16_t)f0.y; t[2]=(bf16_t)f0.z; t[3]=(bf16_t)f0.w;
            t[4]=(bf16_t)f1.x; t[5]=(bf16_t)f1.y; t[6]=(bf16_t)f1.z; t[7]=(bf16_t)f1.w;
            *reinterpret_cast<uint4*>(&dst[m * LDA + sub * 8]) = *reinterpret_cast<const uint4*>(t);
        } else {
            const bf16_t* p = (const bf16_t*)src + (size_t)row * F + sub * 8;
            *reinterpret_cast<uint4*>(&dst[m * LDA + sub * 8]) = *reinterpret_cast<const uint4*>(p);
        }
    }
}

// xg[N, 4F] (gate-interleaved [c][g]) = x[N,F] @ W[4F,F]^T + b0 + b1
template<int F, int G, int NW, bool XF32>
__global__ __launch_bounds__(NW * 64, 2)
void xg_gemm(const void* __restrict__ xsrc_v, const bf16_t* __restrict__ W,
             const float* __restrict__ b0, const float* __restrict__ b1v,
             bf16_t* __restrict__ xg)
{
    constexpr int LDA = F + 8, KK = F / 32, NT = NW * 64;
    constexpr int CPW = G / NW;        // linear out-cols per wave
    constexpr int CT = CPW / 16;
    static_assert(CPW % 16 == 0 && F % 16 == 0, "");
    const int tid = threadIdx.x, wave = tid >> 6, lane = tid & 63;
    const int q = lane >> 4, m16 = lane & 15;
    const int row0 = blockIdx.x * 64;

    __shared__ __align__(16) bf16_t s_x[64 * LDA];
    stage_tile<F, 64, LDA, NT, XF32>(s_x, xsrc_v, row0, tid);
    __syncthreads();

    #pragma unroll
    for (int ct = 0; ct < CT; ++ct) {
        const int lc0 = wave * CPW + ct * 16;   // linear col block (within one gate)
        const int g = lc0 / F, c0 = lc0 - g * F;
        const float bias = b0[lc0 + m16] + b1v[lc0 + m16];
        f32x4 acc[4];
        #pragma unroll
        for (int rt = 0; rt < 4; ++rt)
            #pragma unroll
            for (int r = 0; r < 4; ++r) acc[rt][r] = bias;
        #pragma unroll
        for (int kk = 0; kk < KK; ++kk) {
            const int ko = kk * 32 + q * 8;
            bf16x8 b = *reinterpret_cast<const bf16x8*>(W + (size_t)(lc0 + m16) * F + ko);
            #pragma unroll
            for (int rt = 0; rt < 4; ++rt) {
                bf16x8 a = *reinterpret_cast<const bf16x8*>(&s_x[(rt * 16 + m16) * LDA + ko]);
                acc[rt] = __builtin_amdgcn_mfma_f32_16x16x32_bf16(a, b, acc[rt], 0, 0, 0);
            }
        }
        #pragma unroll
        for (int rt = 0; rt < 4; ++rt)
            #pragma unroll
            for (int r = 0; r < 4; ++r) {
                int row = row0 + rt * 16 + q * 4 + r;
                if (row < NN)
                    xg[(size_t)row * G + (size_t)(c0 + m16) * 4 + g] = (bf16_t)acc[rt][r];
            }
    }
}

// LSTM recurrence over gathered neighbors + fused fc epilogue.
// M=64 nodes/WG, 512 threads = 8 waves: 2 row-groups (32 rows) x 4 col-waves
// (CPW = F/4). ct-loop NOT unrolled; gathers folded into acc init ->
// per-iteration live ~55 arch + 32 AGPR -> no spill.
// gates = gather(xg) + h @ Whh^T ; out = x_self@Wself^T + h_fin@Wneigh^T + b
template<int F, int OUTF, bool RELU, bool XF32, typename OutT>
__global__ __launch_bounds__(512, 2)
void sage_rec(const void* __restrict__ xself_v,
              const bf16_t* __restrict__ xg,
              const int* __restrict__ nbr_idx, const int* __restrict__ deg,
              const bf16_t* __restrict__ Whh,
              const bf16_t* __restrict__ Wself, const bf16_t* __restrict__ Wneigh,
              const float* __restrict__ bout, OutT* __restrict__ outp)
{
    constexpr int M = 64, NT = 512, NW = 8, RT = 2;
    constexpr int LDA = F + 8, KK = F / 32;
    constexpr int CPW = F / 4, CT = CPW / 16, G4 = 4 * F;
    static_assert(CPW % 16 == 0, "");
    static_assert((DMAXX & 1) == 0, "final h must land in buf[0]");
    const int tid = threadIdx.x, wave = tid >> 6, lane = tid & 63;
    const int q = lane >> 4, m16 = lane & 15;
    const int rg = wave >> 2;          // row-group: rows rg*32 .. rg*32+31
    const int cw = wave & 3;           // col-wave:  cols cw*CPW ..
    const int node0 = blockIdx.x * M;

    __shared__ __align__(16) bf16_t s_h[2][M * LDA];   // double-buffered h
    __shared__ int s_idx[M * DMAXX];                   // PRE-SCALED byte offsets
    __shared__ int s_deg[M];

    for (int i = tid; i < M * DMAXX; i += NT) {
        int m = i >> 4;
        int node = node0 + m; if (node >= NN) node = NN - 1;
        int v = nbr_idx[node * DMAXX + (i & 15)];
        if (v < 0) v = 0; if (v >= NN) v = NN - 1;
        s_idx[i] = v * (G4 * 2);       // byte offset of row v in xg
    }
    for (int i = tid; i < M; i += NT) {
        int node = node0 + i; if (node >= NN) node = NN - 1;
        s_deg[i] = deg[node];
    }
    for (int i = tid; i < M * LDA; i += NT) s_h[0][i] = (bf16_t)0.0f;
    __syncthreads();

    // packed degrees: 4x 8-bit per int, one int per row-tile
    int dgp[RT];
    #pragma unroll
    for (int rt = 0; rt < RT; ++rt) {
        int p = 0;
        #pragma unroll
        for (int r = 0; r < 4; ++r)
            p |= (s_deg[rg * 32 + rt * 16 + q * 4 + r] & 255) << (8 * r);
        dgp[rt] = p;
    }

    f32x4 c_[RT][CT];
    #pragma unroll
    for (int rt = 0; rt < RT; ++rt)
        #pragma unroll
        for (int ct = 0; ct < CT; ++ct)
            #pragma unroll
            for (int r = 0; r < 4; ++r) c_[rt][ct][r] = 0.0f;

    const char* xgb = (const char*)xg;

    #pragma unroll 1
    for (int t = 0; t < DMAXX; ++t) {
        const bf16_t* cur = s_h[t & 1];
        bf16_t* nxt = s_h[(t + 1) & 1];
        #pragma unroll 1
        for (int ct = 0; ct < CT; ++ct) {
            const int colb = (cw * CPW + ct * 16 + m16) * 8;   // col byte offset
            // gather gate-init (xg = x@Wih^T + biases) folded straight into
            // the accumulator: u dies immediately, no long live range
            f32x4 acc[RT][4];
            #pragma unroll
            for (int rt = 0; rt < RT; ++rt)
                #pragma unroll
                for (int r = 0; r < 4; ++r) {
                    int off = s_idx[(rg * 32 + rt * 16 + q * 4 + r) * DMAXX + t];
                    u16x4 u = *reinterpret_cast<const u16x4*>(xgb + (unsigned)(off + colb));
                    acc[rt][0][r] = bf2f(u.x);
                    acc[rt][1][r] = bf2f(u.y);
                    acc[rt][2][r] = bf2f(u.z);
                    acc[rt][3][r] = bf2f(u.w);
                }
            #pragma unroll
            for (int kk = 0; kk < KK; ++kk) {
                const int ko = kk * 32 + q * 8;
                bf16x8 ah[RT];
                #pragma unroll
                for (int rt = 0; rt < RT; ++rt)
                    ah[rt] = *reinterpret_cast<const bf16x8*>(
                        &cur[(rg * 32 + rt * 16 + m16) * LDA + ko]);
                #pragma unroll
                for (int g = 0; g < 4; ++g) {
                    bf16x8 bh = *reinterpret_cast<const bf16x8*>(
                        Whh + (size_t)(g * F + cw * CPW + ct * 16 + m16) * F + ko);
                    #pragma unroll
                    for (int rt = 0; rt < RT; ++rt)
                        acc[rt][g] = __builtin_amdgcn_mfma_f32_16x16x32_bf16(ah[rt], bh, acc[rt][g], 0, 0, 0);
                }
            }
            // pointwise LSTM update + masked store:
            //   t <  deg : write h_new (and update c)
            //   t == deg : copy frozen h from cur
            //   t >  deg : skip -- nxt already holds the frozen value
            #pragma unroll
            for (int rt = 0; rt < RT; ++rt)
                #pragma unroll
                for (int r = 0; r < 4; ++r) {
                    float iv = fsig (acc[rt][0][r]);
                    float fv = fsig (acc[rt][1][r]);
                    float gv = ftanh(acc[rt][2][r]);
                    float ov = fsig (acc[rt][3][r]);
                    float cn = fv * c_[rt][ct][r] + iv * gv;
                    float hv = ov * ftanh(cn);
                    const int pos = (rg * 32 + rt * 16 + q * 4 + r) * LDA
                                  + cw * CPW + ct * 16 + m16;
                    const int d = (dgp[rt] >> (8 * r)) & 255;
                    if (t < d) {
                        c_[rt][ct][r] = cn;
                        nxt[pos] = (bf16_t)hv;
                    } else if (t == d) {
                        reinterpret_cast<unsigned short*>(nxt)[pos] =
                            reinterpret_cast<const unsigned short*>(cur)[pos];
                    }
                }
        }
        __syncthreads();   // nxt fully written; cur fully consumed
    }

    // final h is in s_h[0]; stage self-rows into retired s_h[1] for epilogue
    stage_tile<F, M, LDA, NT, XF32>(s_h[1], xself_v, node0, tid);
    __syncthreads();

    // epilogue: out = x_self @ Wself^T + h_fin @ Wneigh^T + bout (+relu)
    constexpr int NCT = OUTF / 16;
    constexpr int TILES = NCT * (M / 16);
    constexpr int TPW = TILES / NW;
    static_assert(TILES % NW == 0, "");
    #pragma unroll
    for (int tt = 0; tt < TPW; ++tt) {
        int tile = wave * TPW + tt;
        int ot = tile % NCT, rtile = tile / NCT;
        f32x4 o;
        o[0] = 0.f; o[1] = 0.f; o[2] = 0.f; o[3] = 0.f;
        #pragma unroll
        for (int kk = 0; kk < KK; ++kk) {
            const int ko = kk * 32 + q * 8;
            bf16x8 axs = *reinterpret_cast<const bf16x8*>(&s_h[1][(rtile * 16 + m16) * LDA + ko]);
            bf16x8 am  = *reinterpret_cast<const bf16x8*>(&s_h[0][(rtile * 16 + m16) * LDA + ko]);
            bf16x8 bs = *reinterpret_cast<const bf16x8*>(Wself  + (size_t)(ot * 16 + m16) * F + ko);
            bf16x8 bn = *reinterpret_cast<const bf16x8*>(Wneigh + (size_t)(ot * 16 + m16) * F + ko);
            o = __builtin_amdgcn_mfma_f32_16x16x32_bf16(axs, bs, o, 0, 0, 0);
            o = __builtin_amdgcn_mfma_f32_16x16x32_bf16(am,  bn, o, 0, 0, 0);
        }
        int ocol = ot * 16 + m16;
        float bias = bout[ocol];
        #pragma unroll
        for (int r = 0; r < 4; ++r) {
            int node = node0 + rtile * 16 + q * 4 + r;
            if (node < NN) {
                float v = o[r] + bias;
                if (RELU) v = fmaxf(v, 0.0f);
                outp[(size_t)node * OUTF + ocol] = (OutT)v;
            }
        }
    }
}

extern "C" void kernel_launch(void* const* d_in, const int* in_sizes, int n_in,
                              void* d_out, int out_size, void* d_ws, size_t ws_size,
                              hipStream_t stream)
{
    const float* feat    = (const float*)d_in[0];
    const int*   nbr     = (const int*)d_in[1];
    const int*   degp    = (const int*)d_in[2];
    const float* Wih1    = (const float*)d_in[3];
    const float* Whh1    = (const float*)d_in[4];
    const float* bih1    = (const float*)d_in[5];
    const float* bhh1    = (const float*)d_in[6];
    const float* Wself1  = (const float*)d_in[7];
    const float* Wneigh1 = (const float*)d_in[8];
    const float* b1      = (const float*)d_in[9];
    const float* Wih2    = (const float*)d_in[10];
    const float* Whh2    = (const float*)d_in[11];
    const float* bih2    = (const float*)d_in[12];
    const float* bhh2    = (const float*)d_in[13];
    const float* Wself2  = (const float*)d_in[14];
    const float* Wneigh2 = (const float*)d_in[15];
    const float* b2      = (const float*)d_in[16];

    bf16_t *hglob, *wglob, *xg1, *xg2;
    hipGetSymbolAddress((void**)&hglob, HIP_SYMBOL(g_hbuf));
    hipGetSymbolAddress((void**)&wglob, HIP_SYMBOL(g_wbuf));
    hipGetSymbolAddress((void**)&xg1,   HIP_SYMBOL(g_xg1));
    hipGetSymbolAddress((void**)&xg2,   HIP_SYMBOL(g_xg2));

    cvt_weights<<<W_TOTAL / 4 / 256, 256, 0, stream>>>(
        Wih1, Whh1, Wself1, Wneigh1, Wih2, Whh2, Wself2, Wneigh2);

    const int grid = (NN + 63) / 64;   // 469 WGs

    xg_gemm<128, 512, 8, true><<<grid, 512, 0, stream>>>(
        feat, wglob + OFF_WIH1, bih1, bhh1, xg1);

    sage_rec<128, 256, true, true, bf16_t><<<grid, 512, 0, stream>>>(
        feat, xg1, nbr, degp, wglob + OFF_WHH1,
        wglob + OFF_WSELF1, wglob + OFF_WNEIGH1, b1, hglob);

    xg_gemm<256, 1024, 8, false><<<grid, 512, 0, stream>>>(
        hglob, wglob + OFF_WIH2, bih2, bhh2, xg2);

    sage_rec<256, 64, false, false, float><<<grid, 512, 0, stream>>>(
        hglob, xg2, nbr, degp, wglob + OFF_WHH2,
        wglob + OFF_WSELF2, wglob + OFF_WNEIGH2, b2, (float*)d_out);
}

// Round 11
// 1744.886 us; speedup vs baseline: 1.6180x; 1.2051x over previous
//
#include <hip/hip_runtime.h>
#include <hip/hip_bf16.h>
#include <stdint.h>

// SAGE (GraphSAGE, LSTM aggregator). f32 I/O, bf16-granularity comparison ->
// bf16 MFMA internally. N=30000, DMAX=16, dims 128 -> 256 -> 64.
// R10 -> R11 (R10: memory finally clean -- WRITE 7.5MB = zero spill, FETCH
// 0.59GB ~= compulsory -- but rec2 REGRESSED to 1577us @ MfmaUtil 6.6%:
// folding gathers into acc-init made the 64-MFMA chain data-dependent on
// 8 random loads -> each ct-iter serializes gather->MFMA):
//   Restore R7's u[]-decoupling WITHOUT its spill: gathers issue at ct-iter
//   top into u (16 VGPRs at RT=2), MFMAs run on zero-init acc (independent),
//   u added in the pointwise tail. s_idx reads hoisted out of the ct loop.
//   Live ~80 arch + 32 AGPR -> still spill-free.
// Verified layouts (learn_hip m89/m91): A[m=lane&15][k=q*8+j],
// D[row=q*4+r][col=lane&15]; W[4F,F] row-major == gemm-BT B-frag layout.

#define NN 30000
#define DMAXX 16

typedef __bf16 bf16_t;
typedef __bf16 bf16x8 __attribute__((ext_vector_type(8)));
typedef float f32x4 __attribute__((ext_vector_type(4)));
typedef unsigned short u16x4 __attribute__((ext_vector_type(4)));

// persistent scratch (fully rewritten every call; no cross-call state reuse)
__device__ __align__(16) bf16_t g_hbuf[(size_t)NN * 256];    // layer-1 output h1
__device__ __align__(16) bf16_t g_xg1[(size_t)NN * 512];     // feat@Wih1^T + biases
__device__ __align__(16) bf16_t g_xg2[(size_t)NN * 1024];    // h1@Wih2^T + biases
__device__ __align__(16) bf16_t g_wbuf[753664];              // bf16 weight copies

#define OFF_WIH1 0
#define OFF_WHH1 65536
#define OFF_WSELF1 131072
#define OFF_WNEIGH1 163840
#define OFF_WIH2 196608
#define OFF_WHH2 458752
#define OFF_WSELF2 720896
#define OFF_WNEIGH2 737280
#define W_TOTAL 753664

__global__ __launch_bounds__(256)
void cvt_weights(const float* __restrict__ s0, const float* __restrict__ s1,
                 const float* __restrict__ s2, const float* __restrict__ s3,
                 const float* __restrict__ s4, const float* __restrict__ s5,
                 const float* __restrict__ s6, const float* __restrict__ s7)
{
    int i = (blockIdx.x * 256 + threadIdx.x) * 4;
    if (i >= W_TOTAL) return;
    const float* src; int off;
    if      (i < OFF_WHH1)   { src = s0; off = OFF_WIH1; }
    else if (i < OFF_WSELF1) { src = s1; off = OFF_WHH1; }
    else if (i < OFF_WNEIGH1){ src = s2; off = OFF_WSELF1; }
    else if (i < OFF_WIH2)   { src = s3; off = OFF_WNEIGH1; }
    else if (i < OFF_WHH2)   { src = s4; off = OFF_WIH2; }
    else if (i < OFF_WSELF2) { src = s5; off = OFF_WHH2; }
    else if (i < OFF_WNEIGH2){ src = s6; off = OFF_WSELF2; }
    else                     { src = s7; off = OFF_WNEIGH2; }
    float4 v = *reinterpret_cast<const float4*>(src + (i - off));
    bf16_t o[4] __attribute__((aligned(8)));
    o[0] = (bf16_t)v.x; o[1] = (bf16_t)v.y; o[2] = (bf16_t)v.z; o[3] = (bf16_t)v.w;
    *reinterpret_cast<uint2*>(&g_wbuf[i]) = *reinterpret_cast<const uint2*>(o);
}

__device__ __forceinline__ float fsig(float x) { return 1.0f / (1.0f + __expf(-x)); }
__device__ __forceinline__ float ftanh(float x) { return 1.0f - 2.0f / (__expf(2.0f * x) + 1.0f); }
__device__ __forceinline__ float bf2f(unsigned short s) {
    union { unsigned u; float f; } v; v.u = ((unsigned)s) << 16; return v.f;
}

// stage an M-row x-tile (global, row-clamped) into LDS as bf16
template<int F, int M, int LDA, int NT, bool XF32>
__device__ __forceinline__ void stage_tile(bf16_t* dst, const void* src, int row0, int tid)
{
    constexpr int UN = F / 8;          // 16B(bf16) units per row
    for (int e = tid; e < M * UN; e += NT) {
        int m = e / UN, sub = e - m * UN;
        int row = row0 + m; if (row >= NN) row = NN - 1;
        if constexpr (XF32) {
            const float* p = (const float*)src + (size_t)row * F + sub * 8;
            float4 f0 = reinterpret_cast<const float4*>(p)[0];
            float4 f1 = reinterpret_cast<const float4*>(p)[1];
            bf16_t t[8] __attribute__((aligned(16)));
            t[0]=(bf16_t)f0.x; t[1]=(bf16_t)f0.y; t[2]=(bf16_t)f0.z; t[3]=(bf16_t)f0.w;
            t[4]=(bf16_t)f1.x; t[5]=(bf16_t)f1.y; t[6]=(bf16_t)f1.z; t[7]=(bf16_t)f1.w;
            *reinterpret_cast<uint4*>(&dst[m * LDA + sub * 8]) = *reinterpret_cast<const uint4*>(t);
        } else {
            const bf16_t* p = (const bf16_t*)src + (size_t)row * F + sub * 8;
            *reinterpret_cast<uint4*>(&dst[m * LDA + sub * 8]) = *reinterpret_cast<const uint4*>(p);
        }
    }
}

// xg[N, 4F] (gate-interleaved [c][g]) = x[N,F] @ W[4F,F]^T + b0 + b1
template<int F, int G, int NW, bool XF32>
__global__ __launch_bounds__(NW * 64, 2)
void xg_gemm(const void* __restrict__ xsrc_v, const bf16_t* __restrict__ W,
             const float* __restrict__ b0, const float* __restrict__ b1v,
             bf16_t* __restrict__ xg)
{
    constexpr int LDA = F + 8, KK = F / 32, NT = NW * 64;
    constexpr int CPW = G / NW;        // linear out-cols per wave
    constexpr int CT = CPW / 16;
    static_assert(CPW % 16 == 0 && F % 16 == 0, "");
    const int tid = threadIdx.x, wave = tid >> 6, lane = tid & 63;
    const int q = lane >> 4, m16 = lane & 15;
    const int row0 = blockIdx.x * 64;

    __shared__ __align__(16) bf16_t s_x[64 * LDA];
    stage_tile<F, 64, LDA, NT, XF32>(s_x, xsrc_v, row0, tid);
    __syncthreads();

    #pragma unroll
    for (int ct = 0; ct < CT; ++ct) {
        const int lc0 = wave * CPW + ct * 16;   // linear col block (within one gate)
        const int g = lc0 / F, c0 = lc0 - g * F;
        const float bias = b0[lc0 + m16] + b1v[lc0 + m16];
        f32x4 acc[4];
        #pragma unroll
        for (int rt = 0; rt < 4; ++rt)
            #pragma unroll
            for (int r = 0; r < 4; ++r) acc[rt][r] = bias;
        #pragma unroll
        for (int kk = 0; kk < KK; ++kk) {
            const int ko = kk * 32 + q * 8;
            bf16x8 b = *reinterpret_cast<const bf16x8*>(W + (size_t)(lc0 + m16) * F + ko);
            #pragma unroll
            for (int rt = 0; rt < 4; ++rt) {
                bf16x8 a = *reinterpret_cast<const bf16x8*>(&s_x[(rt * 16 + m16) * LDA + ko]);
                acc[rt] = __builtin_amdgcn_mfma_f32_16x16x32_bf16(a, b, acc[rt], 0, 0, 0);
            }
        }
        #pragma unroll
        for (int rt = 0; rt < 4; ++rt)
            #pragma unroll
            for (int r = 0; r < 4; ++r) {
                int row = row0 + rt * 16 + q * 4 + r;
                if (row < NN)
                    xg[(size_t)row * G + (size_t)(c0 + m16) * 4 + g] = (bf16_t)acc[rt][r];
            }
    }
}

// LSTM recurrence over gathered neighbors + fused fc epilogue.
// M=64 nodes/WG, 512 threads = 8 waves: 2 row-groups (32 rows) x 4 col-waves
// (CPW = F/4). ct-loop not unrolled; gathers issue into u[] at iter top,
// MFMAs run on zero-init acc (independent), u added in pointwise tail.
// gates = gather(xg) + h @ Whh^T ; out = x_self@Wself^T + h_fin@Wneigh^T + b
template<int F, int OUTF, bool RELU, bool XF32, typename OutT>
__global__ __launch_bounds__(512, 2)
void sage_rec(const void* __restrict__ xself_v,
              const bf16_t* __restrict__ xg,
              const int* __restrict__ nbr_idx, const int* __restrict__ deg,
              const bf16_t* __restrict__ Whh,
              const bf16_t* __restrict__ Wself, const bf16_t* __restrict__ Wneigh,
              const float* __restrict__ bout, OutT* __restrict__ outp)
{
    constexpr int M = 64, NT = 512, NW = 8, RT = 2;
    constexpr int LDA = F + 8, KK = F / 32;
    constexpr int CPW = F / 4, CT = CPW / 16, G4 = 4 * F;
    static_assert(CPW % 16 == 0, "");
    static_assert((DMAXX & 1) == 0, "final h must land in buf[0]");
    const int tid = threadIdx.x, wave = tid >> 6, lane = tid & 63;
    const int q = lane >> 4, m16 = lane & 15;
    const int rg = wave >> 2;          // row-group: rows rg*32 .. rg*32+31
    const int cw = wave & 3;           // col-wave:  cols cw*CPW ..
    const int node0 = blockIdx.x * M;

    __shared__ __align__(16) bf16_t s_h[2][M * LDA];   // double-buffered h
    __shared__ int s_idx[M * DMAXX];                   // PRE-SCALED byte offsets
    __shared__ int s_deg[M];

    for (int i = tid; i < M * DMAXX; i += NT) {
        int m = i >> 4;
        int node = node0 + m; if (node >= NN) node = NN - 1;
        int v = nbr_idx[node * DMAXX + (i & 15)];
        if (v < 0) v = 0; if (v >= NN) v = NN - 1;
        s_idx[i] = v * (G4 * 2);       // byte offset of row v in xg
    }
    for (int i = tid; i < M; i += NT) {
        int node = node0 + i; if (node >= NN) node = NN - 1;
        s_deg[i] = deg[node];
    }
    for (int i = tid; i < M * LDA; i += NT) s_h[0][i] = (bf16_t)0.0f;
    __syncthreads();

    // packed degrees: 4x 8-bit per int, one int per row-tile
    int dgp[RT];
    #pragma unroll
    for (int rt = 0; rt < RT; ++rt) {
        int p = 0;
        #pragma unroll
        for (int r = 0; r < 4; ++r)
            p |= (s_deg[rg * 32 + rt * 16 + q * 4 + r] & 255) << (8 * r);
        dgp[rt] = p;
    }

    f32x4 c_[RT][CT];
    #pragma unroll
    for (int rt = 0; rt < RT; ++rt)
        #pragma unroll
        for (int ct = 0; ct < CT; ++ct)
            #pragma unroll
            for (int r = 0; r < 4; ++r) c_[rt][ct][r] = 0.0f;

    const char* xgb = (const char*)xg;

    #pragma unroll 1
    for (int t = 0; t < DMAXX; ++t) {
        const bf16_t* cur = s_h[t & 1];
        bf16_t* nxt = s_h[(t + 1) & 1];
        // per-row gather byte offsets for this step (ct-invariant)
        int off[RT][4];
        #pragma unroll
        for (int rt = 0; rt < RT; ++rt)
            #pragma unroll
            for (int r = 0; r < 4; ++r)
                off[rt][r] = s_idx[(rg * 32 + rt * 16 + q * 4 + r) * DMAXX + t];

        #pragma unroll 1
        for (int ct = 0; ct < CT; ++ct) {
            const int colb = (cw * CPW + ct * 16 + m16) * 8;   // col byte offset
            // issue gathers early; consumed only in the pointwise tail ->
            // latency overlaps the 64-MFMA block below
            u16x4 u[RT][4];
            #pragma unroll
            for (int rt = 0; rt < RT; ++rt)
                #pragma unroll
                for (int r = 0; r < 4; ++r)
                    u[rt][r] = *reinterpret_cast<const u16x4*>(
                        xgb + (unsigned)(off[rt][r] + colb));

            f32x4 acc[RT][4];
            #pragma unroll
            for (int rt = 0; rt < RT; ++rt)
                #pragma unroll
                for (int g = 0; g < 4; ++g)
                    #pragma unroll
                    for (int r = 0; r < 4; ++r) acc[rt][g][r] = 0.0f;
            #pragma unroll
            for (int kk = 0; kk < KK; ++kk) {
                const int ko = kk * 32 + q * 8;
                bf16x8 ah[RT];
                #pragma unroll
                for (int rt = 0; rt < RT; ++rt)
                    ah[rt] = *reinterpret_cast<const bf16x8*>(
                        &cur[(rg * 32 + rt * 16 + m16) * LDA + ko]);
                #pragma unroll
                for (int g = 0; g < 4; ++g) {
                    bf16x8 bh = *reinterpret_cast<const bf16x8*>(
                        Whh + (size_t)(g * F + cw * CPW + ct * 16 + m16) * F + ko);
                    #pragma unroll
                    for (int rt = 0; rt < RT; ++rt)
                        acc[rt][g] = __builtin_amdgcn_mfma_f32_16x16x32_bf16(ah[rt], bh, acc[rt][g], 0, 0, 0);
                }
            }
            // pointwise LSTM update + masked store:
            //   t <  deg : write h_new (and update c)
            //   t == deg : copy frozen h from cur
            //   t >  deg : skip -- nxt already holds the frozen value
            #pragma unroll
            for (int rt = 0; rt < RT; ++rt)
                #pragma unroll
                for (int r = 0; r < 4; ++r) {
                    float iv = fsig (acc[rt][0][r] + bf2f(u[rt][r].x));
                    float fv = fsig (acc[rt][1][r] + bf2f(u[rt][r].y));
                    float gv = ftanh(acc[rt][2][r] + bf2f(u[rt][r].z));
                    float ov = fsig (acc[rt][3][r] + bf2f(u[rt][r].w));
                    float cn = fv * c_[rt][ct][r] + iv * gv;
                    float hv = ov * ftanh(cn);
                    const int pos = (rg * 32 + rt * 16 + q * 4 + r) * LDA
                                  + cw * CPW + ct * 16 + m16;
                    const int d = (dgp[rt] >> (8 * r)) & 255;
                    if (t < d) {
                        c_[rt][ct][r] = cn;
                        nxt[pos] = (bf16_t)hv;
                    } else if (t == d) {
                        reinterpret_cast<unsigned short*>(nxt)[pos] =
                            reinterpret_cast<const unsigned short*>(cur)[pos];
                    }
                }
        }
        __syncthreads();   // nxt fully written; cur fully consumed
    }

    // final h is in s_h[0]; stage self-rows into retired s_h[1] for epilogue
    stage_tile<F, M, LDA, NT, XF32>(s_h[1], xself_v, node0, tid);
    __syncthreads();

    // epilogue: out = x_self @ Wself^T + h_fin @ Wneigh^T + bout (+relu)
    constexpr int NCT = OUTF / 16;
    constexpr int TILES = NCT * (M / 16);
    constexpr int TPW = TILES / NW;
    static_assert(TILES % NW == 0, "");
    #pragma unroll
    for (int tt = 0; tt < TPW; ++tt) {
        int tile = wave * TPW + tt;
        int ot = tile % NCT, rtile = tile / NCT;
        f32x4 o;
        o[0] = 0.f; o[1] = 0.f; o[2] = 0.f; o[3] = 0.f;
        #pragma unroll
        for (int kk = 0; kk < KK; ++kk) {
            const int ko = kk * 32 + q * 8;
            bf16x8 axs = *reinterpret_cast<const bf16x8*>(&s_h[1][(rtile * 16 + m16) * LDA + ko]);
            bf16x8 am  = *reinterpret_cast<const bf16x8*>(&s_h[0][(rtile * 16 + m16) * LDA + ko]);
            bf16x8 bs = *reinterpret_cast<const bf16x8*>(Wself  + (size_t)(ot * 16 + m16) * F + ko);
            bf16x8 bn = *reinterpret_cast<const bf16x8*>(Wneigh + (size_t)(ot * 16 + m16) * F + ko);
            o = __builtin_amdgcn_mfma_f32_16x16x32_bf16(axs, bs, o, 0, 0, 0);
            o = __builtin_amdgcn_mfma_f32_16x16x32_bf16(am,  bn, o, 0, 0, 0);
        }
        int ocol = ot * 16 + m16;
        float bias = bout[ocol];
        #pragma unroll
        for (int r = 0; r < 4; ++r) {
            int node = node0 + rtile * 16 + q * 4 + r;
            if (node < NN) {
                float v = o[r] + bias;
                if (RELU) v = fmaxf(v, 0.0f);
                outp[(size_t)node * OUTF + ocol] = (OutT)v;
            }
        }
    }
}

extern "C" void kernel_launch(void* const* d_in, const int* in_sizes, int n_in,
                              void* d_out, int out_size, void* d_ws, size_t ws_size,
                              hipStream_t stream)
{
    const float* feat    = (const float*)d_in[0];
    const int*   nbr     = (const int*)d_in[1];
    const int*   degp    = (const int*)d_in[2];
    const float* Wih1    = (const float*)d_in[3];
    const float* Whh1    = (const float*)d_in[4];
    const float* bih1    = (const float*)d_in[5];
    const float* bhh1    = (const float*)d_in[6];
    const float* Wself1  = (const float*)d_in[7];
    const float* Wneigh1 = (const float*)d_in[8];
    const float* b1      = (const float*)d_in[9];
    const float* Wih2    = (const float*)d_in[10];
    const float* Whh2    = (const float*)d_in[11];
    const float* bih2    = (const float*)d_in[12];
    const float* bhh2    = (const float*)d_in[13];
    const float* Wself2  = (const float*)d_in[14];
    const float* Wneigh2 = (const float*)d_in[15];
    const float* b2      = (const float*)d_in[16];

    bf16_t *hglob, *wglob, *xg1, *xg2;
    hipGetSymbolAddress((void**)&hglob, HIP_SYMBOL(g_hbuf));
    hipGetSymbolAddress((void**)&wglob, HIP_SYMBOL(g_wbuf));
    hipGetSymbolAddress((void**)&xg1,   HIP_SYMBOL(g_xg1));
    hipGetSymbolAddress((void**)&xg2,   HIP_SYMBOL(g_xg2));

    cvt_weights<<<W_TOTAL / 4 / 256, 256, 0, stream>>>(
        Wih1, Whh1, Wself1, Wneigh1, Wih2, Whh2, Wself2, Wneigh2);

    const int grid = (NN + 63) / 64;   // 469 WGs

    xg_gemm<128, 512, 8, true><<<grid, 512, 0, stream>>>(
        feat, wglob + OFF_WIH1, bih1, bhh1, xg1);

    sage_rec<128, 256, true, true, bf16_t><<<grid, 512, 0, stream>>>(
        feat, xg1, nbr, degp, wglob + OFF_WHH1,
        wglob + OFF_WSELF1, wglob + OFF_WNEIGH1, b1, hglob);

    xg_gemm<256, 1024, 8, false><<<grid, 512, 0, stream>>>(
        hglob, wglob + OFF_WIH2, bih2, bhh2, xg2);

    sage_rec<256, 64, false, false, float><<<grid, 512, 0, stream>>>(
        hglob, xg2, nbr, degp, wglob + OFF_WHH2,
        wglob + OFF_WSELF2, wglob + OFF_WNEIGH2, b2, (float*)d_out);
}